// Round 1
// baseline (6708.988 us; speedup 1.0000x reference)
//
#include <hip/hip_runtime.h>

typedef _Float16 f16;
typedef _Float16 f16x8 __attribute__((ext_vector_type(8)));
typedef float    f32x4 __attribute__((ext_vector_type(4)));

#define ALPHA 0.2f
#define NSTD  0.05f
#define BB 128
#define TT 1024
#define II 64
#define HH 512
#define OO 10

#define MB   16            // batch elements per block (M of the MFMA, fully used)
#define NB   (BB / MB)     // 8 blocks
#define NAG  13            // wrec K-tiles (of 32) held in registers/AGPRs
#define NLD  3             // wrec K-tiles held in LDS (tiles 13,14,15)
#define RSTR 584           // r_lds row stride in f16 (576 + 8 pad -> 1168 B, 16B-aligned)

__device__ __forceinline__ f32x4 mfma16(f16x8 a, f16x8 b, f32x4 c) {
    return __builtin_amdgcn_mfma_f32_16x16x32_f16(a, b, c, 0, 0, 0);
}

// One block = 16 batch elements, 8 waves. Wave g owns output columns
// [64g, 64g+64) as 4 MFMA N-tiles with FULL K=576 (no cross-wave h reduce).
// Per step: A = [alpha*relu(h_t) | alpha*x_t] (16x576, f16, in LDS, dbuf);
// B = weights as MFMA B-frags: 13 K-tiles in regs/AGPR, 3 in LDS, wi (2 tiles)
// in regs. hs (f32x4[4]) is both state and MFMA accumulator.
__global__ __launch_bounds__(512, 2) void rnn_kernel(
    const float* __restrict__ input, const float* __restrict__ noise,
    const float* __restrict__ wi, const float* __restrict__ si,
    const float* __restrict__ wrec, const float* __restrict__ wo,
    const float* __restrict__ so, const float* __restrict__ h0,
    float* __restrict__ out)
{
    __shared__ __align__(16) f16 r_lds[2][MB][RSTR];   // 36.5 KB (double buffer)
    __shared__ f16x8 wrecL[NLD][32][64];               // 96 KB  (wrec K-tiles 13..15)
    __shared__ f32x4 opart[2][8][64];                  // 16 KB  (out partials, dbuf)

    const int tid = threadIdx.x, l = tid & 63, g = tid >> 6;
    const int lr = l & 15, lg = l >> 4;      // lane: M/N index, K-group
    const int b0 = blockIdx.x * MB;

    // ---- weight fragments (register/AGPR resident across all 1024 steps) ----
    f16x8 bw[NAG][4];   // wrec K-tiles 0..12 for this wave's 4 N-tiles
    f16x8 bwi[2][4];    // wi (k 512..575), si folded
    f16x8 bwo[2];       // wo*so/alpha for the out-MFMA (K-tiles 2g, 2g+1)

#pragma unroll
    for (int kt = 0; kt < NAG; ++kt)
#pragma unroll
        for (int nt = 0; nt < 4; ++nt) {
            // B[k][n=j] = wrec[j][k]; j = (4g+nt)*16 + lr, k = kt*32 + lg*8 + jj
            const float* wp = wrec + (size_t)((4*g + nt)*16 + lr)*HH + kt*32 + lg*8;
            float4 a0 = *(const float4*)wp;
            float4 a1 = *(const float4*)(wp + 4);
            f16x8 v;
            v[0]=(f16)a0.x; v[1]=(f16)a0.y; v[2]=(f16)a0.z; v[3]=(f16)a0.w;
            v[4]=(f16)a1.x; v[5]=(f16)a1.y; v[6]=(f16)a1.z; v[7]=(f16)a1.w;
            bw[kt][nt] = v;
        }
#pragma unroll
    for (int ktL = 0; ktL < NLD; ++ktL)
#pragma unroll
        for (int c = 0; c < 4; ++c) {
            const int nt = c*8 + g;          // all 32 N-tiles covered by 8 waves
            const float* wp = wrec + (size_t)(nt*16 + lr)*HH + (NAG + ktL)*32 + lg*8;
            float4 a0 = *(const float4*)wp;
            float4 a1 = *(const float4*)(wp + 4);
            f16x8 v;
            v[0]=(f16)a0.x; v[1]=(f16)a0.y; v[2]=(f16)a0.z; v[3]=(f16)a0.w;
            v[4]=(f16)a1.x; v[5]=(f16)a1.y; v[6]=(f16)a1.z; v[7]=(f16)a1.w;
            wrecL[ktL][nt][l] = v;
        }
#pragma unroll
    for (int k2 = 0; k2 < 2; ++k2)
#pragma unroll
        for (int nt = 0; nt < 4; ++nt) {
            const int hcol = (4*g + nt)*16 + lr;
            f16x8 v;
#pragma unroll
            for (int jj = 0; jj < 8; ++jj) {
                const int i = k2*32 + lg*8 + jj;       // 0..63
                v[jj] = (f16)(wi[(size_t)i*HH + hcol] * si[i]);
            }
            bwi[k2][nt] = v;
        }
    {
        const float s = (lr < OO) ? so[lr] * (1.0f/ALPHA) : 0.0f;
#pragma unroll
        for (int k2 = 0; k2 < 2; ++k2) {
            f16x8 v;
#pragma unroll
            for (int jj = 0; jj < 8; ++jj) {
                const int k = (2*g + k2)*32 + lg*8 + jj;   // < 512
                v[jj] = (f16)((lr < OO) ? wo[(size_t)k*OO + lr] * s : 0.0f);
            }
            bwo[k2] = v;
        }
    }

    // ---- state: hs[nt][rr] = h[batch 4*lg+rr][col (4g+nt)*16+lr] (C/D layout) ----
    f32x4 hs[4];
#pragma unroll
    for (int nt = 0; nt < 4; ++nt) {
        const float v = h0[(4*g + nt)*16 + lr];
        hs[nt] = f32x4{v, v, v, v};
    }

    // noise: 4 row pointers (one per rr), 16 scalars prefetched one step ahead
    const float* nptr[4];
#pragma unroll
    for (int rr = 0; rr < 4; ++rr)
        nptr[rr] = noise + (size_t)(b0 + 4*lg + rr)*TT*HH + 64*g + lr;
    float nz[4][4];
#pragma unroll
    for (int nt = 0; nt < 4; ++nt)
#pragma unroll
        for (int rr = 0; rr < 4; ++rr) nz[nt][rr] = nptr[rr][nt*16];   // n_0

    // x staging: thread covers (bb, ii..ii+1); prefetched one step ahead
    const int bb = tid >> 5, ii = (tid & 31) * 2;
    const float* xbase = input + (size_t)(b0 + bb)*TT*II + ii;
    float2 xv = *(const float2*)xbase;                                 // x_0

    // publish r_0 = alpha*relu(h0) and alpha*x_0 into buffer 0
#pragma unroll
    for (int nt = 0; nt < 4; ++nt)
#pragma unroll
        for (int rr = 0; rr < 4; ++rr)
            r_lds[0][4*lg + rr][(4*g + nt)*16 + lr] =
                (f16)(ALPHA * fmaxf(hs[nt][rr], 0.0f));
    r_lds[0][bb][512 + ii]     = (f16)(ALPHA * xv.x);
    r_lds[0][bb][512 + ii + 1] = (f16)(ALPHA * xv.y);
    const float* xq = xbase + II;
    xv = *(const float2*)xq;  xq += II;                                // x_1

    __syncthreads();

    int cur = 0;
#pragma unroll 1
    for (int t = 0; t < TT; ++t) {
        const f16* rb = &r_lds[cur][0][0] + lr*RSTR + lg*8;

        // h pre-accumulate: (1-a)h + sigma*n_t  (becomes the MFMA C operand)
#pragma unroll
        for (int nt = 0; nt < 4; ++nt) {
            f32x4 a = hs[nt];
#pragma unroll
            for (int rr = 0; rr < 4; ++rr)
                a[rr] = (1.0f - ALPHA)*a[rr] + NSTD*nz[nt][rr];
            hs[nt] = a;
        }
        // prefetch n_{t+1}
        if (t + 1 < TT) {
#pragma unroll
            for (int rr = 0; rr < 4; ++rr) nptr[rr] += HH;
#pragma unroll
            for (int nt = 0; nt < 4; ++nt)
#pragma unroll
                for (int rr = 0; rr < 4; ++rr) nz[nt][rr] = nptr[rr][nt*16];
        }

        // out-MFMA: out[t-1] = relu(h_t) @ wo_full, from r_lds (alpha folded out)
        {
            const f16x8 aA = *(const f16x8*)(rb + (2*g)*32);
            const f16x8 aB = *(const f16x8*)(rb + (2*g)*32 + 32);
            f32x4 oacc = mfma16(aA, bwo[0], f32x4{0.f, 0.f, 0.f, 0.f});
            oacc = mfma16(aB, bwo[1], oacc);
            opart[cur][g][l] = oacc;
        }

        // main chain: h_{t+1} += alpha*(r_t@Wrec^T + x_t@Wi'), K = 18 tiles
#pragma unroll
        for (int kt = 0; kt < NAG; ++kt) {
            const f16x8 a = *(const f16x8*)(rb + kt*32);
#pragma unroll
            for (int nt = 0; nt < 4; ++nt)
                hs[nt] = mfma16(a, bw[kt][nt], hs[nt]);
        }
#pragma unroll
        for (int ktL = 0; ktL < NLD; ++ktL) {
            const f16x8 a = *(const f16x8*)(rb + (NAG + ktL)*32);
#pragma unroll
            for (int nt = 0; nt < 4; ++nt)
                hs[nt] = mfma16(a, wrecL[ktL][4*g + nt][l], hs[nt]);
        }
#pragma unroll
        for (int k2 = 0; k2 < 2; ++k2) {
            const f16x8 a = *(const f16x8*)(rb + (16 + k2)*32);
#pragma unroll
            for (int nt = 0; nt < 4; ++nt)
                hs[nt] = mfma16(a, bwi[k2][nt], hs[nt]);
        }

        // publish r_{t+1} (+ alpha*x_{t+1}) into the other buffer
        const int nxt = cur ^ 1;
#pragma unroll
        for (int nt = 0; nt < 4; ++nt)
#pragma unroll
            for (int rr = 0; rr < 4; ++rr)
                r_lds[nxt][4*lg + rr][(4*g + nt)*16 + lr] =
                    (f16)(ALPHA * fmaxf(hs[nt][rr], 0.0f));
        if (t + 1 < TT) {
            r_lds[nxt][bb][512 + ii]     = (f16)(ALPHA * xv.x);
            r_lds[nxt][bb][512 + ii + 1] = (f16)(ALPHA * xv.y);
            if (t + 2 < TT) { xv = *(const float2*)xq; xq += II; }
        }

        __syncthreads();   // publishes r_lds[nxt] and opart[cur]

        if (g == 7 && t > 0) {
            f32x4 s = opart[cur][0][l];
#pragma unroll
            for (int w = 1; w < 8; ++w) s += opart[cur][w][l];
            if (lr < OO) {
#pragma unroll
                for (int rr = 0; rr < 4; ++rr)
                    out[((size_t)(b0 + 4*lg + rr)*TT + (t - 1))*OO + lr] = s[rr];
            }
        }
        cur = nxt;
    }

    // drain: out[T-1] from r_lds[cur] = alpha*relu(h_T)
    {
        const f16* rb = &r_lds[cur][0][0] + lr*RSTR + lg*8;
        const f16x8 aA = *(const f16x8*)(rb + (2*g)*32);
        const f16x8 aB = *(const f16x8*)(rb + (2*g)*32 + 32);
        f32x4 oacc = mfma16(aA, bwo[0], f32x4{0.f, 0.f, 0.f, 0.f});
        oacc = mfma16(aB, bwo[1], oacc);
        opart[cur][g][l] = oacc;
    }
    __syncthreads();
    if (g == 7) {
        f32x4 s = opart[cur][0][l];
#pragma unroll
        for (int w = 1; w < 8; ++w) s += opart[cur][w][l];
        if (lr < OO) {
#pragma unroll
            for (int rr = 0; rr < 4; ++rr)
                out[((size_t)(b0 + 4*lg + rr)*TT + (TT - 1))*OO + lr] = s[rr];
        }
    }
}

extern "C" void kernel_launch(void* const* d_in, const int* in_sizes, int n_in,
                              void* d_out, int out_size, void* d_ws, size_t ws_size,
                              hipStream_t stream) {
    const float* input = (const float*)d_in[0];
    const float* noise = (const float*)d_in[1];
    const float* wi    = (const float*)d_in[2];
    const float* si    = (const float*)d_in[3];
    const float* wrec  = (const float*)d_in[4];
    const float* wo    = (const float*)d_in[5];
    const float* so    = (const float*)d_in[6];
    const float* h0    = (const float*)d_in[7];
    float* out = (float*)d_out;
    (void)d_ws; (void)ws_size; (void)in_sizes; (void)n_in; (void)out_size;

    rnn_kernel<<<dim3(NB), dim3(512), 0, stream>>>(
        input, noise, wi, si, wrec, wo, so, h0, out);
}